// Round 5
// baseline (247.976 us; speedup 1.0000x reference)
//
#include <hip/hip_runtime.h>
#include <cstdint>

#define S_LEN 4096
#define D_MODEL 1024
#define NHEAD 16
#define HDIM 64

typedef __bf16 bf16_t;
typedef __bf16 bf16x8 __attribute__((ext_vector_type(8)));
typedef __bf16 bf16x4 __attribute__((ext_vector_type(4)));
typedef float floatx4 __attribute__((ext_vector_type(4)));

// 1/sqrt(64) * log2(e): folded into Q at projection time so softmax uses exp2.
#define QSCALE 0.18033688011112042f

__device__ __forceinline__ void lds_cp16(void* lds, const void* g) {
    __builtin_amdgcn_global_load_lds(
        (const __attribute__((address_space(1))) unsigned int*)g,
        (__attribute__((address_space(3))) unsigned int*)lds,
        16, 0, 0);
}

// ---------------- fused prep: x fp32->bf16 (blocks 0..4095), W transpose (4096..5119) --
__global__ __launch_bounds__(256) void k_prep(const float* __restrict__ x,
                                              const float* __restrict__ Wq,
                                              const float* __restrict__ Wk,
                                              const float* __restrict__ Wv,
                                              const float* __restrict__ Wo,
                                              bf16_t* __restrict__ xb,
                                              bf16_t* __restrict__ WtQKV,
                                              bf16_t* __restrict__ WtO) {
    const int bx = blockIdx.x;
    if (bx < 4096) {
        int i = bx * 256 + threadIdx.x;
        float4 v = ((const float4*)x)[i];
        bf16x4 o;
        o[0] = (bf16_t)v.x; o[1] = (bf16_t)v.y; o[2] = (bf16_t)v.z; o[3] = (bf16_t)v.w;
        *(bf16x4*)(xb + (size_t)i * 4) = o;
        return;
    }
    __shared__ float lds[64][65];
    const int i = bx - 4096;
    const int z = i >> 8, rem = i & 255;
    const float* W = (z == 0) ? Wq : (z == 1) ? Wk : (z == 2) ? Wv : Wo;
    bf16_t* Wt = (z < 3) ? (WtQKV + (size_t)z * 1048576) : WtO;
    const int k0 = (rem >> 4) * 64, n0 = (rem & 15) * 64;
    const int t = threadIdx.x, cl = t & 63, rl = t >> 6;
#pragma unroll
    for (int r = 0; r < 16; ++r)
        lds[r * 4 + rl][cl] = W[(size_t)(k0 + r * 4 + rl) * 1024 + n0 + cl];
    __syncthreads();
#pragma unroll
    for (int r = 0; r < 16; ++r)
        Wt[(size_t)(n0 + r * 4 + rl) * 1024 + k0 + cl] = (bf16_t)lds[cl][r * 4 + rl];
}

// ---------------- 128x128 bf16 GEMM, Bt[n][k] input (m97 structure) ----------------
// MODE 0: plain fp32 output to Cout [4096][1024]
// MODE 1: QKV epilogue. Each block's 128 cols lie in ONE group (by>>3):
//         0 -> Q [h][s][d] (scaled), 1 -> K [h][s][d], 2 -> V written as Vt [h][d][s].
template <int MODE>
__global__ __launch_bounds__(256) void k_gemm(const bf16_t* __restrict__ A,
                                              const bf16_t* __restrict__ Bt,
                                              float* __restrict__ Cout,
                                              bf16_t* __restrict__ Qb,
                                              bf16_t* __restrict__ Kb,
                                              bf16_t* __restrict__ Vt) {
    __shared__ __align__(16) bf16_t sA[128 * 32];
    __shared__ __align__(16) bf16_t sB[128 * 32];
    const int t = threadIdx.x, w = t >> 6, lane = t & 63, quad = lane >> 4, l15 = lane & 15;
    const int m0 = blockIdx.x * 128, n0 = blockIdx.y * 128;
    const int wm = w >> 1, wn = w & 1;

    floatx4 acc[4][4];
#pragma unroll
    for (int i = 0; i < 4; ++i)
#pragma unroll
        for (int j = 0; j < 4; ++j)
            acc[i][j] = floatx4{0.f, 0.f, 0.f, 0.f};

    for (int kb = 0; kb < 32; ++kb) {
        __syncthreads();
#pragma unroll
        for (int r = 0; r < 2; ++r) {
            int c = t + 256 * r;
            int row = c >> 2, kq = c & 3;
            lds_cp16(&sA[w * 512 + r * 2048],
                     A + (size_t)(m0 + row) * 1024 + kb * 32 + kq * 8);
            lds_cp16(&sB[w * 512 + r * 2048],
                     Bt + (size_t)(n0 + row) * 1024 + kb * 32 + kq * 8);
        }
        __syncthreads();
        bf16x8 af[4], bfr[4];
#pragma unroll
        for (int i = 0; i < 4; ++i)
            af[i] = *(const bf16x8*)&sA[(wm * 64 + i * 16 + l15) * 32 + quad * 8];
#pragma unroll
        for (int j = 0; j < 4; ++j)
            bfr[j] = *(const bf16x8*)&sB[(wn * 64 + j * 16 + l15) * 32 + quad * 8];
#pragma unroll
        for (int i = 0; i < 4; ++i)
#pragma unroll
            for (int j = 0; j < 4; ++j)
                acc[i][j] = __builtin_amdgcn_mfma_f32_16x16x32_bf16(af[i], bfr[j],
                                                                    acc[i][j], 0, 0, 0);
    }

    const int mrow = m0 + wm * 64 + quad * 4;
    if (MODE == 0) {
        const int ncol = n0 + wn * 64 + l15;
#pragma unroll
        for (int i = 0; i < 4; ++i)
#pragma unroll
            for (int j = 0; j < 4; ++j)
#pragma unroll
                for (int r = 0; r < 4; ++r)
                    Cout[(size_t)(mrow + i * 16 + r) * 1024 + ncol + j * 16] = acc[i][j][r];
    } else {
        const int g = (int)blockIdx.y >> 3;                       // 0:Q 1:K 2:V
        const int ncbase = ((int)blockIdx.y & 7) * 128 + wn * 64 + l15;
        if (g == 2) {
            // V -> Vt [h][d][s]; 4 consecutive s pack into one 8B store
#pragma unroll
            for (int j = 0; j < 4; ++j) {
                int nc = ncbase + j * 16;
                int hh = nc >> 6, dd = nc & 63;
                bf16_t* dst = Vt + (size_t)hh * 262144 + (size_t)dd * 4096;
#pragma unroll
                for (int i = 0; i < 4; ++i) {
                    bf16x4 pk;
                    pk[0] = (bf16_t)acc[i][j][0]; pk[1] = (bf16_t)acc[i][j][1];
                    pk[2] = (bf16_t)acc[i][j][2]; pk[3] = (bf16_t)acc[i][j][3];
                    *(bf16x4*)&dst[mrow + i * 16] = pk;
                }
            }
        } else {
            bf16_t* base = g ? Kb : Qb;
            const float sc = g ? 1.0f : QSCALE;
#pragma unroll
            for (int j = 0; j < 4; ++j) {
                int nc = ncbase + j * 16;
                int hh = nc >> 6, dd = nc & 63;
#pragma unroll
                for (int i = 0; i < 4; ++i)
#pragma unroll
                    for (int r = 0; r < 4; ++r)
                        base[(size_t)hh * 262144 + (size_t)(mrow + i * 16 + r) * 64 + dd] =
                            (bf16_t)(acc[i][j][r] * sc);
            }
        }
    }
}

// ---------------- flash attention, causal, Br=128, Bc=64 ----------------
// S^T scheme, fixed-m softmax. 4 waves x 32 q-rows: K/V fragment reads amortized
// over 2x q vs Br=64. LDS: K dbuf 16K + V 8K + P 16K = 40960 B -> 4 blocks/CU.
__global__ __launch_bounds__(256, 4) void k_attn(const bf16_t* __restrict__ Qb,
                                                 const bf16_t* __restrict__ Kb,
                                                 const bf16_t* __restrict__ Vt,
                                                 bf16_t* __restrict__ Ob) {
    __shared__ __align__(16) bf16_t Ks[2][64 * 64];
    __shared__ __align__(16) bf16_t Vts[64 * 64];      // [d][key], swizzled
    __shared__ __align__(16) bf16_t Ps[4][32 * 64];    // per-wave P [q][k], swizzled
    const int h = blockIdx.y;
    // co-resident blocks (n, n+256) get complementary qb: iter counts sum to 66
    const int qb = (h & 8) ? (int)blockIdx.x : (31 - (int)blockIdx.x);
    const int t = threadIdx.x, w = t >> 6, quad = (t & 63) >> 4, l15 = t & 15;
    const bf16_t* Qh = Qb + (size_t)h * 262144;
    const bf16_t* Kh = Kb + (size_t)h * 262144;
    const bf16_t* Vth = Vt + (size_t)h * 262144;
    bf16_t* PsW = &Ps[w][0];

    // Q B-frags straight from global: wave owns q = qb*128 + w*32 + qt*16 + l15
    const bf16_t* Qrow = Qh + (size_t)(qb * 128 + w * 32 + l15) * 64;
    bf16x8 bq[2][2];
#pragma unroll
    for (int qt = 0; qt < 2; ++qt)
#pragma unroll
        for (int kh = 0; kh < 2; ++kh)
            bq[qt][kh] = *(const bf16x8*)(Qrow + qt * 1024 + kh * 32 + quad * 8);

    float l_s[2] = {0.f, 0.f};
    floatx4 o_acc[2][4];
#pragma unroll
    for (int qt = 0; qt < 2; ++qt)
#pragma unroll
        for (int j = 0; j < 4; ++j) o_acc[qt][j] = floatx4{0.f, 0.f, 0.f, 0.f};

#define STAGE_K(b, kb_)                                                            \
    {                                                                              \
        _Pragma("unroll") for (int r = 0; r < 2; ++r) {                            \
            int c = t + 256 * r;                                                   \
            int row = c >> 3, sw = (c & 7) ^ (row & 7);                            \
            lds_cp16(&Ks[b][c * 8], Kh + (size_t)(kb_) * 4096 + row * 64 + sw * 8);\
        }                                                                          \
    }
#define STAGE_V(kb_)                                                               \
    {                                                                              \
        _Pragma("unroll") for (int r = 0; r < 2; ++r) {                            \
            int c = t + 256 * r;                                                   \
            int row = c >> 3, sw = (c & 7) ^ (row & 7);                            \
            lds_cp16(&Vts[c * 8], Vth + (size_t)row * 4096 + (kb_) * 64 + sw * 8); \
        }                                                                          \
    }

    const int kend = 2 * qb + 1;
    const int qmax = qb * 128 + w * 32 + 31;   // highest q this wave owns

    STAGE_K(0, 0)
    for (int kb = 0; kb <= kend; ++kb) {
        const int buf = kb & 1;
        __syncthreads();  // K[buf] staged; prior-iter LDS reads drained
        STAGE_V(kb)       // V first (oldest vm ops)
        if (kb < kend) STAGE_K(buf ^ 1, kb + 1)
        const bool active = (kb * 64 <= qmax);  // wave-uniform

        if (active) {
            // S^T = K Q^T: A = K rows (64 keys), B = Q (2 q-subtiles in regs)
            floatx4 st[2][4];
#pragma unroll
            for (int j = 0; j < 4; ++j) {
                int rk = j * 16 + l15;
                bf16x8 a0 = *(const bf16x8*)&Ks[buf][rk * 64 + ((quad ^ (rk & 7)) * 8)];
                bf16x8 a1 = *(const bf16x8*)&Ks[buf][rk * 64 + (((quad + 4) ^ (rk & 7)) * 8)];
#pragma unroll
                for (int qt = 0; qt < 2; ++qt) {
                    floatx4 z = {0.f, 0.f, 0.f, 0.f};
                    st[qt][j] = __builtin_amdgcn_mfma_f32_16x16x32_bf16(a0, bq[qt][0], z, 0, 0, 0);
                    st[qt][j] = __builtin_amdgcn_mfma_f32_16x16x32_bf16(a1, bq[qt][1], st[qt][j], 0, 0, 0);
                }
            }
            if (kb >= 2 * qb) {  // only the two diagonal-straddling tiles need masking
#pragma unroll
                for (int qt = 0; qt < 2; ++qt) {
                    int qg = qb * 128 + w * 32 + qt * 16 + l15;
#pragma unroll
                    for (int j = 0; j < 4; ++j)
#pragma unroll
                        for (int r = 0; r < 4; ++r) {
                            int keyg = kb * 64 + j * 16 + quad * 4 + r;
                            if (keyg > qg) st[qt][j][r] = -1e30f;
                        }
                }
            }
            // fixed-m softmax: p = exp2(s); pack P to wave-private swizzled LDS
#pragma unroll
            for (int qt = 0; qt < 2; ++qt) {
                float a0 = 0.f, a1 = 0.f, a2 = 0.f, a3 = 0.f;
#pragma unroll
                for (int j = 0; j < 4; ++j) {
                    float p0 = exp2f(st[qt][j][0]);
                    float p1 = exp2f(st[qt][j][1]);
                    float p2 = exp2f(st[qt][j][2]);
                    float p3 = exp2f(st[qt][j][3]);
                    a0 += p0; a1 += p1; a2 += p2; a3 += p3;
                    bf16x4 pk;
                    pk[0] = (bf16_t)p0; pk[1] = (bf16_t)p1;
                    pk[2] = (bf16_t)p2; pk[3] = (bf16_t)p3;
                    int c = j * 4 + quad;  // 8B chunk within the 128B row
                    *(bf16x4*)&PsW[(qt * 16 + l15) * 64 + (((c >> 1) ^ (l15 & 7)) * 8) +
                                   (c & 1) * 4] = pk;
                }
                l_s[qt] += (a0 + a1) + (a2 + a3);
            }
        }
        // V[kb] landed (V loads are the 2 oldest; K prefetch may stay in flight)
        if (kb < kend) asm volatile("s_waitcnt vmcnt(2)" ::: "memory");
        else           asm volatile("s_waitcnt vmcnt(0)" ::: "memory");
        if (active) {
            // O += P V: bv reads shared across both q-subtiles
#pragma unroll
            for (int kh = 0; kh < 2; ++kh) {
                int pc = kh * 4 + quad;  // 16B chunk 0..7
                bf16x8 pa0 = *(const bf16x8*)&PsW[l15 * 64 + ((pc ^ (l15 & 7)) * 8)];
                bf16x8 pa1 = *(const bf16x8*)&PsW[(16 + l15) * 64 + ((pc ^ (l15 & 7)) * 8)];
#pragma unroll
                for (int j = 0; j < 4; ++j) {
                    int rd = j * 16 + l15;
                    bf16x8 bv = *(const bf16x8*)&Vts[rd * 64 + ((pc ^ (rd & 7)) * 8)];
                    o_acc[0][j] = __builtin_amdgcn_mfma_f32_16x16x32_bf16(pa0, bv, o_acc[0][j], 0, 0, 0);
                    o_acc[1][j] = __builtin_amdgcn_mfma_f32_16x16x32_bf16(pa1, bv, o_acc[1][j], 0, 0, 0);
                }
            }
        }
    }
    // epilogue: reduce l over the 4 quad-copies, broadcast, normalize, write
#pragma unroll
    for (int qt = 0; qt < 2; ++qt) {
        float l = l_s[qt];
        l += __shfl_xor(l, 16);
        l += __shfl_xor(l, 32);
#pragma unroll
        for (int r = 0; r < 4; ++r) {
            float inv = 1.0f / __shfl(l, quad * 4 + r);
            int rowg = qb * 128 + w * 32 + qt * 16 + quad * 4 + r;
#pragma unroll
            for (int j = 0; j < 4; ++j)
                Ob[(size_t)rowg * 1024 + h * 64 + j * 16 + l15] =
                    (bf16_t)(o_acc[qt][j][r] * inv);
        }
    }
#undef STAGE_K
#undef STAGE_V
}

extern "C" void kernel_launch(void* const* d_in, const int* in_sizes, int n_in,
                              void* d_out, int out_size, void* d_ws, size_t ws_size,
                              hipStream_t stream) {
    const float* x  = (const float*)d_in[0];
    const float* Wq = (const float*)d_in[1];
    const float* Wk = (const float*)d_in[2];
    const float* Wv = (const float*)d_in[3];
    const float* Wo = (const float*)d_in[4];

    bf16_t* ws = (bf16_t*)d_ws;
    bf16_t* Xb    = ws;                    // 4096x1024
    bf16_t* WtQKV = Xb + 4194304;          // 3072x1024 (Wq^T|Wk^T|Wv^T)
    bf16_t* WtO   = WtQKV + 3145728;       // 1024x1024
    bf16_t* Qb    = WtO + 1048576;         // [16][4096][64], pre-scaled
    bf16_t* Kb    = Qb + 4194304;          // [16][4096][64]
    bf16_t* Vt    = Kb + 4194304;          // [16][64][4096]
    bf16_t* Ob    = Vt + 4194304;          // [4096][1024]
    float* out = (float*)d_out;

    k_prep<<<5120, 256, 0, stream>>>(x, Wq, Wk, Wv, Wo, Xb, WtQKV, WtO);
    k_gemm<1><<<dim3(32, 24), 256, 0, stream>>>(Xb, WtQKV, nullptr, Qb, Kb, Vt);
    k_attn<<<dim3(32, 16), 256, 0, stream>>>(Qb, Kb, Vt, Ob);
    k_gemm<0><<<dim3(32, 8), 256, 0, stream>>>(Ob, WtO, out, nullptr, nullptr, nullptr);
}

// Round 6
// 221.287 us; speedup vs baseline: 1.1206x; 1.1206x over previous
//
#include <hip/hip_runtime.h>
#include <cstdint>

#define S_LEN 4096
#define D_MODEL 1024
#define NHEAD 16
#define HDIM 64

typedef __bf16 bf16_t;
typedef __bf16 bf16x8 __attribute__((ext_vector_type(8)));
typedef __bf16 bf16x4 __attribute__((ext_vector_type(4)));
typedef float floatx4 __attribute__((ext_vector_type(4)));

// 1/sqrt(64) * log2(e): folded into Q at projection time so softmax uses exp2.
#define QSCALE 0.18033688011112042f

__device__ __forceinline__ void lds_cp16(void* lds, const void* g) {
    __builtin_amdgcn_global_load_lds(
        (const __attribute__((address_space(1))) unsigned int*)g,
        (__attribute__((address_space(3))) unsigned int*)lds,
        16, 0, 0);
}

// ---------------- fused prep: x fp32->bf16 (blocks 0..4095), W transpose (4096..5119) --
__global__ __launch_bounds__(256) void k_prep(const float* __restrict__ x,
                                              const float* __restrict__ Wq,
                                              const float* __restrict__ Wk,
                                              const float* __restrict__ Wv,
                                              const float* __restrict__ Wo,
                                              bf16_t* __restrict__ xb,
                                              bf16_t* __restrict__ WtQKV,
                                              bf16_t* __restrict__ WtO) {
    const int bx = blockIdx.x;
    if (bx < 4096) {
        int i = bx * 256 + threadIdx.x;
        float4 v = ((const float4*)x)[i];
        bf16x4 o;
        o[0] = (bf16_t)v.x; o[1] = (bf16_t)v.y; o[2] = (bf16_t)v.z; o[3] = (bf16_t)v.w;
        *(bf16x4*)(xb + (size_t)i * 4) = o;
        return;
    }
    __shared__ float lds[64][65];
    const int i = bx - 4096;
    const int z = i >> 8, rem = i & 255;
    const float* W = (z == 0) ? Wq : (z == 1) ? Wk : (z == 2) ? Wv : Wo;
    bf16_t* Wt = (z < 3) ? (WtQKV + (size_t)z * 1048576) : WtO;
    const int k0 = (rem >> 4) * 64, n0 = (rem & 15) * 64;
    const int t = threadIdx.x, cl = t & 63, rl = t >> 6;
#pragma unroll
    for (int r = 0; r < 16; ++r)
        lds[r * 4 + rl][cl] = W[(size_t)(k0 + r * 4 + rl) * 1024 + n0 + cl];
    __syncthreads();
#pragma unroll
    for (int r = 0; r < 16; ++r)
        Wt[(size_t)(n0 + r * 4 + rl) * 1024 + k0 + cl] = (bf16_t)lds[cl][r * 4 + rl];
}

// ---------------- 128x128 bf16 GEMM, Bt[n][k] input (m97 structure) ----------------
// MODE 0: plain fp32 output to Cout [4096][1024]
// MODE 1: QKV epilogue. Each block's 128 cols lie in ONE group (by>>3):
//         0 -> Q [h][s][d] (scaled), 1 -> K [h][s][d], 2 -> V tiled [h][kb][d][64].
template <int MODE>
__global__ __launch_bounds__(256) void k_gemm(const bf16_t* __restrict__ A,
                                              const bf16_t* __restrict__ Bt,
                                              float* __restrict__ Cout,
                                              bf16_t* __restrict__ Qb,
                                              bf16_t* __restrict__ Kb,
                                              bf16_t* __restrict__ Vt) {
    __shared__ __align__(16) bf16_t sA[128 * 32];
    __shared__ __align__(16) bf16_t sB[128 * 32];
    const int t = threadIdx.x, w = t >> 6, lane = t & 63, quad = lane >> 4, l15 = lane & 15;
    const int m0 = blockIdx.x * 128, n0 = blockIdx.y * 128;
    const int wm = w >> 1, wn = w & 1;

    floatx4 acc[4][4];
#pragma unroll
    for (int i = 0; i < 4; ++i)
#pragma unroll
        for (int j = 0; j < 4; ++j)
            acc[i][j] = floatx4{0.f, 0.f, 0.f, 0.f};

    for (int kb = 0; kb < 32; ++kb) {
        __syncthreads();
#pragma unroll
        for (int r = 0; r < 2; ++r) {
            int c = t + 256 * r;
            int row = c >> 2, kq = c & 3;
            lds_cp16(&sA[w * 512 + r * 2048],
                     A + (size_t)(m0 + row) * 1024 + kb * 32 + kq * 8);
            lds_cp16(&sB[w * 512 + r * 2048],
                     Bt + (size_t)(n0 + row) * 1024 + kb * 32 + kq * 8);
        }
        __syncthreads();
        bf16x8 af[4], bfr[4];
#pragma unroll
        for (int i = 0; i < 4; ++i)
            af[i] = *(const bf16x8*)&sA[(wm * 64 + i * 16 + l15) * 32 + quad * 8];
#pragma unroll
        for (int j = 0; j < 4; ++j)
            bfr[j] = *(const bf16x8*)&sB[(wn * 64 + j * 16 + l15) * 32 + quad * 8];
#pragma unroll
        for (int i = 0; i < 4; ++i)
#pragma unroll
            for (int j = 0; j < 4; ++j)
                acc[i][j] = __builtin_amdgcn_mfma_f32_16x16x32_bf16(af[i], bfr[j],
                                                                    acc[i][j], 0, 0, 0);
    }

    const int mrow = m0 + wm * 64 + quad * 4;
    if (MODE == 0) {
        const int ncol = n0 + wn * 64 + l15;
#pragma unroll
        for (int i = 0; i < 4; ++i)
#pragma unroll
            for (int j = 0; j < 4; ++j)
#pragma unroll
                for (int r = 0; r < 4; ++r)
                    Cout[(size_t)(mrow + i * 16 + r) * 1024 + ncol + j * 16] = acc[i][j][r];
    } else {
        const int g = (int)blockIdx.y >> 3;                       // 0:Q 1:K 2:V
        const int ncbase = ((int)blockIdx.y & 7) * 128 + wn * 64 + l15;
        if (g == 2) {
            // V -> tiled [h][kb64][d][64 keys]; 4 consecutive s = one 8B store
#pragma unroll
            for (int j = 0; j < 4; ++j) {
                int nc = ncbase + j * 16;
                int hh = nc >> 6, dd = nc & 63;
                bf16_t* dst = Vt + (size_t)hh * 262144 + (size_t)dd * 64;
#pragma unroll
                for (int i = 0; i < 4; ++i) {
                    int s0r = mrow + i * 16;
                    bf16x4 pk;
                    pk[0] = (bf16_t)acc[i][j][0]; pk[1] = (bf16_t)acc[i][j][1];
                    pk[2] = (bf16_t)acc[i][j][2]; pk[3] = (bf16_t)acc[i][j][3];
                    *(bf16x4*)&dst[(size_t)(s0r >> 6) * 4096 + (s0r & 63)] = pk;
                }
            }
        } else {
            bf16_t* base = g ? Kb : Qb;
            const float sc = g ? 1.0f : QSCALE;
#pragma unroll
            for (int j = 0; j < 4; ++j) {
                int nc = ncbase + j * 16;
                int hh = nc >> 6, dd = nc & 63;
#pragma unroll
                for (int i = 0; i < 4; ++i)
#pragma unroll
                    for (int r = 0; r < 4; ++r)
                        base[(size_t)hh * 262144 + (size_t)(mrow + i * 16 + r) * 64 + dd] =
                            (bf16_t)(acc[i][j][r] * sc);
            }
        }
    }
}

// ---------------- flash attention, causal, Br=128, Bc=64, SPLIT-K x2 ----------------
// Fixed-m softmax => partials are additive: block (qb, split, h) computes
// un-normalized O-partial (bf16) + l-partial over its key range. Splits have
// equal work (qb+1 tiles each). Heavy blocks dispatched first.
// LDS: K dbuf 16K + V 8K + P 16K = 40960 B -> 4 blocks/CU; grid 1024 -> 16 waves/CU.
__global__ __launch_bounds__(256, 4) void k_attn(const bf16_t* __restrict__ Qb,
                                                 const bf16_t* __restrict__ Kb,
                                                 const bf16_t* __restrict__ Vt,
                                                 bf16_t* __restrict__ OP0,
                                                 bf16_t* __restrict__ OP1,
                                                 float* __restrict__ Lp) {
    __shared__ __align__(16) bf16_t Ks[2][64 * 64];
    __shared__ __align__(16) bf16_t Vts[64 * 64];      // [d][key], swizzled
    __shared__ __align__(16) bf16_t Ps[4][32 * 64];    // per-wave P [q][k], swizzled
    const int bid = blockIdx.x;
    const int qb = 31 - (bid >> 5);                    // heavy (32-iter) blocks first
    const int sp = bid & 1, h = (bid & 31) >> 1;
    const int t = threadIdx.x, w = t >> 6, quad = (t & 63) >> 4, l15 = t & 15;
    const bf16_t* Qh = Qb + (size_t)h * 262144;
    const bf16_t* Kh = Kb + (size_t)h * 262144;
    const bf16_t* Vth = Vt + (size_t)h * 262144;
    bf16_t* PsW = &Ps[w][0];

    // Q B-frags straight from global: wave owns q = qb*128 + w*32 + qt*16 + l15
    const bf16_t* Qrow = Qh + (size_t)(qb * 128 + w * 32 + l15) * 64;
    bf16x8 bq[2][2];
#pragma unroll
    for (int qt = 0; qt < 2; ++qt)
#pragma unroll
        for (int kh = 0; kh < 2; ++kh)
            bq[qt][kh] = *(const bf16x8*)(Qrow + qt * 1024 + kh * 32 + quad * 8);

    float l_s[2] = {0.f, 0.f};
    floatx4 o_acc[2][4];
#pragma unroll
    for (int qt = 0; qt < 2; ++qt)
#pragma unroll
        for (int j = 0; j < 4; ++j) o_acc[qt][j] = floatx4{0.f, 0.f, 0.f, 0.f};

#define STAGE_K(b, kb_)                                                            \
    {                                                                              \
        _Pragma("unroll") for (int r = 0; r < 2; ++r) {                            \
            int c = t + 256 * r;                                                   \
            int row = c >> 3, sw = (c & 7) ^ (row & 7);                            \
            lds_cp16(&Ks[b][c * 8], Kh + (size_t)(kb_) * 4096 + row * 64 + sw * 8);\
        }                                                                          \
    }
#define STAGE_V(kb_)                                                               \
    {                                                                              \
        _Pragma("unroll") for (int r = 0; r < 2; ++r) {                            \
            int c = t + 256 * r;                                                   \
            int row = c >> 3, sw = (c & 7) ^ (row & 7);                            \
            lds_cp16(&Vts[c * 8], Vth + (size_t)(kb_) * 4096 + row * 64 + sw * 8); \
        }                                                                          \
    }

    const int t0 = sp ? (qb + 1) : 0;      // first key-tile of this split
    const int nIter = qb + 1;              // equal work across splits
    const int qmax = qb * 128 + w * 32 + 31;

    STAGE_K(0, t0)
    for (int it = 0; it < nIter; ++it) {
        const int kb = t0 + it;
        const int buf = it & 1;
        __syncthreads();  // K[buf] staged; prior-iter LDS reads drained
        STAGE_V(kb)       // V first (oldest vm ops)
        if (it + 1 < nIter) STAGE_K(buf ^ 1, kb + 1)
        const bool active = (kb * 64 <= qmax);  // wave-uniform

        if (active) {
            // S^T = K Q^T: A = K rows (64 keys), B = Q (2 q-subtiles in regs)
            floatx4 st[2][4];
#pragma unroll
            for (int j = 0; j < 4; ++j) {
                int rk = j * 16 + l15;
                bf16x8 a0 = *(const bf16x8*)&Ks[buf][rk * 64 + ((quad ^ (rk & 7)) * 8)];
                bf16x8 a1 = *(const bf16x8*)&Ks[buf][rk * 64 + (((quad + 4) ^ (rk & 7)) * 8)];
#pragma unroll
                for (int qt = 0; qt < 2; ++qt) {
                    floatx4 z = {0.f, 0.f, 0.f, 0.f};
                    st[qt][j] = __builtin_amdgcn_mfma_f32_16x16x32_bf16(a0, bq[qt][0], z, 0, 0, 0);
                    st[qt][j] = __builtin_amdgcn_mfma_f32_16x16x32_bf16(a1, bq[qt][1], st[qt][j], 0, 0, 0);
                }
            }
            if (kb >= 2 * qb) {  // only the diagonal-straddling tiles need masking
#pragma unroll
                for (int qt = 0; qt < 2; ++qt) {
                    int qg = qb * 128 + w * 32 + qt * 16 + l15;
#pragma unroll
                    for (int j = 0; j < 4; ++j)
#pragma unroll
                        for (int r = 0; r < 4; ++r) {
                            int keyg = kb * 64 + j * 16 + quad * 4 + r;
                            if (keyg > qg) st[qt][j][r] = -1e30f;
                        }
                }
            }
            // fixed-m softmax: p = exp2(s); pack P to wave-private swizzled LDS
#pragma unroll
            for (int qt = 0; qt < 2; ++qt) {
                float a0 = 0.f, a1 = 0.f, a2 = 0.f, a3 = 0.f;
#pragma unroll
                for (int j = 0; j < 4; ++j) {
                    float p0 = exp2f(st[qt][j][0]);
                    float p1 = exp2f(st[qt][j][1]);
                    float p2 = exp2f(st[qt][j][2]);
                    float p3 = exp2f(st[qt][j][3]);
                    a0 += p0; a1 += p1; a2 += p2; a3 += p3;
                    bf16x4 pk;
                    pk[0] = (bf16_t)p0; pk[1] = (bf16_t)p1;
                    pk[2] = (bf16_t)p2; pk[3] = (bf16_t)p3;
                    int c = j * 4 + quad;  // 8B chunk within the 128B row
                    *(bf16x4*)&PsW[(qt * 16 + l15) * 64 + (((c >> 1) ^ (l15 & 7)) * 8) +
                                   (c & 1) * 4] = pk;
                }
                l_s[qt] += (a0 + a1) + (a2 + a3);
            }
        }
        // V[kb] landed (V loads are the 2 oldest; K prefetch may stay in flight)
        if (it + 1 < nIter) asm volatile("s_waitcnt vmcnt(2)" ::: "memory");
        else                asm volatile("s_waitcnt vmcnt(0)" ::: "memory");
        if (active) {
            // O += P V: bv reads shared across both q-subtiles
#pragma unroll
            for (int kh = 0; kh < 2; ++kh) {
                int pc = kh * 4 + quad;  // 16B chunk 0..7
                bf16x8 pa0 = *(const bf16x8*)&PsW[l15 * 64 + ((pc ^ (l15 & 7)) * 8)];
                bf16x8 pa1 = *(const bf16x8*)&PsW[(16 + l15) * 64 + ((pc ^ (l15 & 7)) * 8)];
#pragma unroll
                for (int j = 0; j < 4; ++j) {
                    int rd = j * 16 + l15;
                    bf16x8 bv = *(const bf16x8*)&Vts[rd * 64 + ((pc ^ (rd & 7)) * 8)];
                    o_acc[0][j] = __builtin_amdgcn_mfma_f32_16x16x32_bf16(pa0, bv, o_acc[0][j], 0, 0, 0);
                    o_acc[1][j] = __builtin_amdgcn_mfma_f32_16x16x32_bf16(pa1, bv, o_acc[1][j], 0, 0, 0);
                }
            }
        }
    }
    // epilogue: write un-normalized bf16 O-partial + fp32 l-partial
    bf16_t* OPx = sp ? OP1 : OP0;
#pragma unroll
    for (int qt = 0; qt < 2; ++qt) {
        float l = l_s[qt];
        l += __shfl_xor(l, 16);
        l += __shfl_xor(l, 32);
        if (quad == 0)
            Lp[sp * 65536 + h * 4096 + (qb * 128 + w * 32 + qt * 16 + l15)] = l;
#pragma unroll
        for (int r = 0; r < 4; ++r) {
            int rowg = qb * 128 + w * 32 + qt * 16 + quad * 4 + r;
#pragma unroll
            for (int j = 0; j < 4; ++j)
                OPx[(size_t)rowg * 1024 + h * 64 + j * 16 + l15] = (bf16_t)o_acc[qt][j][r];
        }
    }
#undef STAGE_K
#undef STAGE_V
}

// ---------------- combine split partials: Ob = (O0+O1)/(l0+l1) ----------------
__global__ __launch_bounds__(256) void k_combine(const bf16_t* __restrict__ OP0,
                                                 const bf16_t* __restrict__ OP1,
                                                 const float* __restrict__ Lp,
                                                 bf16_t* __restrict__ Ob) {
    int gi = (blockIdx.x * 256 + threadIdx.x) * 4;
    int q = gi >> 10, hh = (gi & 1023) >> 6;
    float inv = 1.0f / (Lp[hh * 4096 + q] + Lp[65536 + hh * 4096 + q]);
    bf16x4 a = *(const bf16x4*)(OP0 + gi);
    bf16x4 b = *(const bf16x4*)(OP1 + gi);
    bf16x4 o;
#pragma unroll
    for (int r = 0; r < 4; ++r)
        o[r] = (bf16_t)(((float)a[r] + (float)b[r]) * inv);
    *(bf16x4*)(Ob + gi) = o;
}

extern "C" void kernel_launch(void* const* d_in, const int* in_sizes, int n_in,
                              void* d_out, int out_size, void* d_ws, size_t ws_size,
                              hipStream_t stream) {
    const float* x  = (const float*)d_in[0];
    const float* Wq = (const float*)d_in[1];
    const float* Wk = (const float*)d_in[2];
    const float* Wv = (const float*)d_in[3];
    const float* Wo = (const float*)d_in[4];

    bf16_t* ws = (bf16_t*)d_ws;
    bf16_t* Xb    = ws;                    // 4096x1024 bf16 (dead after gemm1 -> OP0)
    bf16_t* WtQKV = Xb + 4194304;          // 3072x1024 (dead after gemm1 -> Lp fp32)
    bf16_t* WtO   = WtQKV + 3145728;       // 1024x1024
    bf16_t* Qb    = WtO + 1048576;         // [16][4096][64], pre-scaled
    bf16_t* Kb    = Qb + 4194304;          // [16][4096][64]
    bf16_t* Vt    = Kb + 4194304;          // [16][64 kb][64 d][64 k] tiled
    bf16_t* Ob    = Vt + 4194304;          // [4096][1024]
    bf16_t* OP1   = Ob + 4194304;          // split-1 partial
    bf16_t* OP0   = Xb;                    // split-0 partial (reuse)
    float*  Lp    = (float*)WtQKV;         // [2][16][4096] l partials (reuse)
    float* out = (float*)d_out;

    k_prep<<<5120, 256, 0, stream>>>(x, Wq, Wk, Wv, Wo, Xb, WtQKV, WtO);
    k_gemm<1><<<dim3(32, 24), 256, 0, stream>>>(Xb, WtQKV, nullptr, Qb, Kb, Vt);
    k_attn<<<1024, 256, 0, stream>>>(Qb, Kb, Vt, OP0, OP1, Lp);
    k_combine<<<4096, 256, 0, stream>>>(OP0, OP1, Lp, Ob);
    k_gemm<0><<<dim3(32, 8), 256, 0, stream>>>(Ob, WtO, out, nullptr, nullptr, nullptr);
}